// Round 16
// baseline (106.346 us; speedup 1.0000x reference)
//
#include <hip/hip_runtime.h>
#include <stdint.h>

#define NCLS 14
#define BATCH 2
#define NUM_BINS (BATCH * NCLS)   // 28
#define KSPREAD 64                // per-bin atomic spread factor

// d_ws layout: float fsum[28*64] | int fcnt[28*64] | unsigned counter

__global__ void kd16_zero(float* __restrict__ fsum, int* __restrict__ fcnt,
                          unsigned* __restrict__ counter) {
    int i = blockIdx.x * blockDim.x + threadIdx.x;   // grid covers 1792 exactly
    fsum[i] = 0.0f;
    fcnt[i] = 0;
    if (i == 0) *counter = 0u;
}

// R13 core (asm-MLP loads, per-wave LDS bins, ballot counts) + fused
// last-block finalize (rocPRIM pattern): saves the third kernel launch.
__global__ __launch_bounds__(256) void kd16_kl(
        const float* __restrict__ S, const float* __restrict__ T,
        const int* __restrict__ gt,
        float* __restrict__ fsum, int* __restrict__ fcnt,
        unsigned* __restrict__ counter, float* __restrict__ out,
        int N, int grid) {
    __shared__ float lsum[4][16];
    __shared__ int lcnt[4][16];
    __shared__ int isLast;
    const int tid = threadIdx.x;
    const int wave = tid >> 6, lane = tid & 63;
    if (tid < 64) { lsum[tid >> 4][tid & 15] = 0.0f; lcnt[tid >> 4][tid & 15] = 0; }
    __syncthreads();

    // b from blockIdx only -> block-uniform -> SGPR channel bases (saddr form).
    const int b = ((unsigned)blockIdx.x * 1024u >= (unsigned)N) ? 1 : 0;
    const int gid = blockIdx.x * blockDim.x + tid;
    const int v0 = gid * 4;                       // 4 voxels per thread
    const int n = v0 - b * N;

    const float* Sb = S + (size_t)b * NCLS * N;   // uniform (SGPR pair)
    const float* Tb = T + (size_t)b * NCLS * N;   // uniform (SGPR pair)
    const uint32_t voff = (uint32_t)n * 4u;       // per-lane byte offset

    float4 sv[NCLS], tv[NCLS];

    asm volatile(
        "global_load_dwordx4 %[d0], %[vo], %[p0]\n\t"
        "global_load_dwordx4 %[d1], %[vo], %[p1]\n\t"
        "global_load_dwordx4 %[d2], %[vo], %[p2]\n\t"
        "global_load_dwordx4 %[d3], %[vo], %[p3]\n\t"
        "global_load_dwordx4 %[d4], %[vo], %[p4]\n\t"
        "global_load_dwordx4 %[d5], %[vo], %[p5]\n\t"
        "global_load_dwordx4 %[d6], %[vo], %[p6]\n\t"
        : [d0]"=v"(sv[0]), [d1]"=v"(sv[1]), [d2]"=v"(sv[2]), [d3]"=v"(sv[3]),
          [d4]"=v"(sv[4]), [d5]"=v"(sv[5]), [d6]"=v"(sv[6])
        : [vo]"v"(voff),
          [p0]"s"(Sb + 0*(size_t)N), [p1]"s"(Sb + 1*(size_t)N),
          [p2]"s"(Sb + 2*(size_t)N), [p3]"s"(Sb + 3*(size_t)N),
          [p4]"s"(Sb + 4*(size_t)N), [p5]"s"(Sb + 5*(size_t)N),
          [p6]"s"(Sb + 6*(size_t)N));
    asm volatile(
        "global_load_dwordx4 %[d0], %[vo], %[p0]\n\t"
        "global_load_dwordx4 %[d1], %[vo], %[p1]\n\t"
        "global_load_dwordx4 %[d2], %[vo], %[p2]\n\t"
        "global_load_dwordx4 %[d3], %[vo], %[p3]\n\t"
        "global_load_dwordx4 %[d4], %[vo], %[p4]\n\t"
        "global_load_dwordx4 %[d5], %[vo], %[p5]\n\t"
        "global_load_dwordx4 %[d6], %[vo], %[p6]\n\t"
        : [d0]"=v"(sv[7]), [d1]"=v"(sv[8]), [d2]"=v"(sv[9]), [d3]"=v"(sv[10]),
          [d4]"=v"(sv[11]), [d5]"=v"(sv[12]), [d6]"=v"(sv[13])
        : [vo]"v"(voff),
          [p0]"s"(Sb + 7*(size_t)N), [p1]"s"(Sb + 8*(size_t)N),
          [p2]"s"(Sb + 9*(size_t)N), [p3]"s"(Sb + 10*(size_t)N),
          [p4]"s"(Sb + 11*(size_t)N), [p5]"s"(Sb + 12*(size_t)N),
          [p6]"s"(Sb + 13*(size_t)N));
    asm volatile(
        "global_load_dwordx4 %[d0], %[vo], %[p0]\n\t"
        "global_load_dwordx4 %[d1], %[vo], %[p1]\n\t"
        "global_load_dwordx4 %[d2], %[vo], %[p2]\n\t"
        "global_load_dwordx4 %[d3], %[vo], %[p3]\n\t"
        "global_load_dwordx4 %[d4], %[vo], %[p4]\n\t"
        "global_load_dwordx4 %[d5], %[vo], %[p5]\n\t"
        "global_load_dwordx4 %[d6], %[vo], %[p6]\n\t"
        : [d0]"=v"(tv[0]), [d1]"=v"(tv[1]), [d2]"=v"(tv[2]), [d3]"=v"(tv[3]),
          [d4]"=v"(tv[4]), [d5]"=v"(tv[5]), [d6]"=v"(tv[6])
        : [vo]"v"(voff),
          [p0]"s"(Tb + 0*(size_t)N), [p1]"s"(Tb + 1*(size_t)N),
          [p2]"s"(Tb + 2*(size_t)N), [p3]"s"(Tb + 3*(size_t)N),
          [p4]"s"(Tb + 4*(size_t)N), [p5]"s"(Tb + 5*(size_t)N),
          [p6]"s"(Tb + 6*(size_t)N));
    asm volatile(
        "global_load_dwordx4 %[d0], %[vo], %[p0]\n\t"
        "global_load_dwordx4 %[d1], %[vo], %[p1]\n\t"
        "global_load_dwordx4 %[d2], %[vo], %[p2]\n\t"
        "global_load_dwordx4 %[d3], %[vo], %[p3]\n\t"
        "global_load_dwordx4 %[d4], %[vo], %[p4]\n\t"
        "global_load_dwordx4 %[d5], %[vo], %[p5]\n\t"
        "global_load_dwordx4 %[d6], %[vo], %[p6]\n\t"
        : [d0]"=v"(tv[7]), [d1]"=v"(tv[8]), [d2]"=v"(tv[9]), [d3]"=v"(tv[10]),
          [d4]"=v"(tv[11]), [d5]"=v"(tv[12]), [d6]"=v"(tv[13])
        : [vo]"v"(voff),
          [p0]"s"(Tb + 7*(size_t)N), [p1]"s"(Tb + 8*(size_t)N),
          [p2]"s"(Tb + 9*(size_t)N), [p3]"s"(Tb + 10*(size_t)N),
          [p4]"s"(Tb + 11*(size_t)N), [p5]"s"(Tb + 12*(size_t)N),
          [p6]"s"(Tb + 13*(size_t)N));

    int4 g = *reinterpret_cast<const int4*>(gt + v0);

    asm volatile("s_waitcnt vmcnt(0)" ::: "memory");
    __builtin_amdgcn_sched_barrier(0);

    float Zs[4] = {0,0,0,0}, Zt[4] = {0,0,0,0};
    float At[4] = {0,0,0,0}, As[4] = {0,0,0,0};
#pragma unroll
    for (int c = 0; c < NCLS; ++c) {
        float s[4] = {sv[c].x, sv[c].y, sv[c].z, sv[c].w};
        float t[4] = {tv[c].x, tv[c].y, tv[c].z, tv[c].w};
#pragma unroll
        for (int v = 0; v < 4; ++v) {
            float et = __expf(t[v]);
            Zt[v] += et;
            At[v] = fmaf(et, t[v], At[v]);
            As[v] = fmaf(et, s[v], As[v]);
            Zs[v] += __expf(s[v]);
        }
    }

    int cls[4];
    cls[0] = min(max(g.x, 0), NCLS - 1);
    cls[1] = min(max(g.y, 0), NCLS - 1);
    cls[2] = min(max(g.z, 0), NCLS - 1);
    cls[3] = min(max(g.w, 0), NCLS - 1);

#pragma unroll
    for (int v = 0; v < 4; ++v) {
        float kl = (At[v] - As[v]) / Zt[v] - __logf(Zt[v]) + __logf(Zs[v]);
        atomicAdd(&lsum[wave][cls[v]], kl);
    }
#pragma unroll
    for (int c = 0; c < NCLS; ++c) {
        int nvc = 0;
#pragma unroll
        for (int v = 0; v < 4; ++v)
            nvc += __popcll(__ballot(cls[v] == c));
        if (lane == 0) lcnt[wave][c] = nvc;
    }

    __syncthreads();
    if (tid < NCLS) {
        float s = lsum[0][tid] + lsum[1][tid] + lsum[2][tid] + lsum[3][tid];
        int nn = lcnt[0][tid] + lcnt[1][tid] + lcnt[2][tid] + lcnt[3][tid];
        const int slot = blockIdx.x & (KSPREAD - 1);
        const int bin = b * NCLS + tid;
        atomicAdd(&fsum[bin * KSPREAD + slot], s);
        atomicAdd(&fcnt[bin * KSPREAD + slot], nn);
    }

    // ---- last-block finalize (rocPRIM pattern): saves the 3rd launch ----
    if (tid == 0) {
        __threadfence();                          // publish this block's atomics
        unsigned done = atomicAdd(counter, 1u);
        isLast = (done == (unsigned)grid - 1u) ? 1 : 0;
    }
    __syncthreads();
    if (isLast) {
        __threadfence();                          // acquire: invalidate stale lines
        __shared__ float terms[NUM_BINS];
        if (tid < NUM_BINS) {
            const volatile float* fp = fsum + tid * KSPREAD;
            const volatile int* cp = fcnt + tid * KSPREAD;
            float s = 0.0f; int n = 0;
#pragma unroll
            for (int i = 0; i < KSPREAD; ++i) { s += fp[i]; n += cp[i]; }
            const int cls = tid % NCLS;           // bin = b*NCLS + cls
            terms[tid] = (cls != 0 && n > 0) ? s / ((float)NCLS * (float)n) : 0.0f;
        }
        __syncthreads();
        if (tid == 0) {
            float loss = 0.0f;
#pragma unroll
            for (int i = 0; i < NUM_BINS; ++i) loss += terms[i];
            out[0] = loss;                        // TAU^2 = 1, LOSS_WEIGHT = 1
        }
    }
}

extern "C" void kernel_launch(void* const* d_in, const int* in_sizes, int n_in,
                              void* d_out, int out_size, void* d_ws, size_t ws_size,
                              hipStream_t stream) {
    const float* S = (const float*)d_in[0];
    const float* T = (const float*)d_in[1];
    const int* gt = (const int*)d_in[2];
    float* out = (float*)d_out;

    float* fsum = (float*)d_ws;
    int* fcnt = (int*)((char*)d_ws + NUM_BINS * KSPREAD * sizeof(float));
    unsigned* counter = (unsigned*)((char*)d_ws + 2 * NUM_BINS * KSPREAD * sizeof(float));

    const int totalVox = in_sizes[2];       // 1,769,472 = 1728 * 1024
    const int N = totalVox / BATCH;         // 884,736 (divisible by 1024)

    const int block = 256;
    const int grid = totalVox / (block * 4);  // 1728 blocks, 4 voxels/thread

    kd16_zero<<<(NUM_BINS * KSPREAD) / 256, 256, 0, stream>>>(fsum, fcnt, counter);
    kd16_kl<<<grid, block, 0, stream>>>(S, T, gt, fsum, fcnt, counter, out, N, grid);
}

// Round 17
// 45.478 us; speedup vs baseline: 2.3384x; 2.3384x over previous
//
#include <hip/hip_runtime.h>
#include <stdint.h>

#define NCLS 14
#define BATCH 2
#define NUM_BINS (BATCH * NCLS)   // 28
#define KSPREAD 64                // per-bin atomic spread factor

// REVERT to round-13 best (44.2 us): 3-kernel structure, asm-MLP loads,
// per-wave LDS sum bins, ballot counts, 64-way-spread global atomics,
// fully-unrolled finalizer. Renamed kd17 to force a fresh binary.
// d_ws layout: float fsum[NUM_BINS*KSPREAD] | int fcnt[NUM_BINS*KSPREAD]

__global__ void kd17_zero(float* __restrict__ fsum, int* __restrict__ fcnt) {
    int i = blockIdx.x * blockDim.x + threadIdx.x;   // grid covers 1792 exactly
    fsum[i] = 0.0f;
    fcnt[i] = 0;
}

__global__ __launch_bounds__(256) void kd17_kl(
        const float* __restrict__ S, const float* __restrict__ T,
        const int* __restrict__ gt,
        float* __restrict__ fsum, int* __restrict__ fcnt,
        int N /* voxels per batch image */) {
    __shared__ float lsum[4][16];
    __shared__ int lcnt[4][16];
    const int tid = threadIdx.x;
    const int wave = tid >> 6, lane = tid & 63;
    if (tid < 64) { lsum[tid >> 4][tid & 15] = 0.0f; lcnt[tid >> 4][tid & 15] = 0; }
    __syncthreads();

    // b from blockIdx only -> block-uniform -> SGPR channel bases (saddr form).
    const int b = ((unsigned)blockIdx.x * 1024u >= (unsigned)N) ? 1 : 0;
    const int gid = blockIdx.x * blockDim.x + tid;
    const int v0 = gid * 4;                       // 4 voxels per thread
    const int n = v0 - b * N;

    const float* Sb = S + (size_t)b * NCLS * N;   // uniform (SGPR pair)
    const float* Tb = T + (size_t)b * NCLS * N;   // uniform (SGPR pair)
    const uint32_t voff = (uint32_t)n * 4u;       // per-lane byte offset

    float4 sv[NCLS], tv[NCLS];

    // ---- 28 independent dwordx4 loads, issued densely via inline asm. ----
    asm volatile(
        "global_load_dwordx4 %[d0], %[vo], %[p0]\n\t"
        "global_load_dwordx4 %[d1], %[vo], %[p1]\n\t"
        "global_load_dwordx4 %[d2], %[vo], %[p2]\n\t"
        "global_load_dwordx4 %[d3], %[vo], %[p3]\n\t"
        "global_load_dwordx4 %[d4], %[vo], %[p4]\n\t"
        "global_load_dwordx4 %[d5], %[vo], %[p5]\n\t"
        "global_load_dwordx4 %[d6], %[vo], %[p6]\n\t"
        : [d0]"=v"(sv[0]), [d1]"=v"(sv[1]), [d2]"=v"(sv[2]), [d3]"=v"(sv[3]),
          [d4]"=v"(sv[4]), [d5]"=v"(sv[5]), [d6]"=v"(sv[6])
        : [vo]"v"(voff),
          [p0]"s"(Sb + 0*(size_t)N), [p1]"s"(Sb + 1*(size_t)N),
          [p2]"s"(Sb + 2*(size_t)N), [p3]"s"(Sb + 3*(size_t)N),
          [p4]"s"(Sb + 4*(size_t)N), [p5]"s"(Sb + 5*(size_t)N),
          [p6]"s"(Sb + 6*(size_t)N));
    asm volatile(
        "global_load_dwordx4 %[d0], %[vo], %[p0]\n\t"
        "global_load_dwordx4 %[d1], %[vo], %[p1]\n\t"
        "global_load_dwordx4 %[d2], %[vo], %[p2]\n\t"
        "global_load_dwordx4 %[d3], %[vo], %[p3]\n\t"
        "global_load_dwordx4 %[d4], %[vo], %[p4]\n\t"
        "global_load_dwordx4 %[d5], %[vo], %[p5]\n\t"
        "global_load_dwordx4 %[d6], %[vo], %[p6]\n\t"
        : [d0]"=v"(sv[7]), [d1]"=v"(sv[8]), [d2]"=v"(sv[9]), [d3]"=v"(sv[10]),
          [d4]"=v"(sv[11]), [d5]"=v"(sv[12]), [d6]"=v"(sv[13])
        : [vo]"v"(voff),
          [p0]"s"(Sb + 7*(size_t)N), [p1]"s"(Sb + 8*(size_t)N),
          [p2]"s"(Sb + 9*(size_t)N), [p3]"s"(Sb + 10*(size_t)N),
          [p4]"s"(Sb + 11*(size_t)N), [p5]"s"(Sb + 12*(size_t)N),
          [p6]"s"(Sb + 13*(size_t)N));
    asm volatile(
        "global_load_dwordx4 %[d0], %[vo], %[p0]\n\t"
        "global_load_dwordx4 %[d1], %[vo], %[p1]\n\t"
        "global_load_dwordx4 %[d2], %[vo], %[p2]\n\t"
        "global_load_dwordx4 %[d3], %[vo], %[p3]\n\t"
        "global_load_dwordx4 %[d4], %[vo], %[p4]\n\t"
        "global_load_dwordx4 %[d5], %[vo], %[p5]\n\t"
        "global_load_dwordx4 %[d6], %[vo], %[p6]\n\t"
        : [d0]"=v"(tv[0]), [d1]"=v"(tv[1]), [d2]"=v"(tv[2]), [d3]"=v"(tv[3]),
          [d4]"=v"(tv[4]), [d5]"=v"(tv[5]), [d6]"=v"(tv[6])
        : [vo]"v"(voff),
          [p0]"s"(Tb + 0*(size_t)N), [p1]"s"(Tb + 1*(size_t)N),
          [p2]"s"(Tb + 2*(size_t)N), [p3]"s"(Tb + 3*(size_t)N),
          [p4]"s"(Tb + 4*(size_t)N), [p5]"s"(Tb + 5*(size_t)N),
          [p6]"s"(Tb + 6*(size_t)N));
    asm volatile(
        "global_load_dwordx4 %[d0], %[vo], %[p0]\n\t"
        "global_load_dwordx4 %[d1], %[vo], %[p1]\n\t"
        "global_load_dwordx4 %[d2], %[vo], %[p2]\n\t"
        "global_load_dwordx4 %[d3], %[vo], %[p3]\n\t"
        "global_load_dwordx4 %[d4], %[vo], %[p4]\n\t"
        "global_load_dwordx4 %[d5], %[vo], %[p5]\n\t"
        "global_load_dwordx4 %[d6], %[vo], %[p6]\n\t"
        : [d0]"=v"(tv[7]), [d1]"=v"(tv[8]), [d2]"=v"(tv[9]), [d3]"=v"(tv[10]),
          [d4]"=v"(tv[11]), [d5]"=v"(tv[12]), [d6]"=v"(tv[13])
        : [vo]"v"(voff),
          [p0]"s"(Tb + 7*(size_t)N), [p1]"s"(Tb + 8*(size_t)N),
          [p2]"s"(Tb + 9*(size_t)N), [p3]"s"(Tb + 10*(size_t)N),
          [p4]"s"(Tb + 11*(size_t)N), [p5]"s"(Tb + 12*(size_t)N),
          [p6]"s"(Tb + 13*(size_t)N));

    int4 g = *reinterpret_cast<const int4*>(gt + v0);

    asm volatile("s_waitcnt vmcnt(0)" ::: "memory");
    __builtin_amdgcn_sched_barrier(0);

    float Zs[4] = {0,0,0,0}, Zt[4] = {0,0,0,0};
    float At[4] = {0,0,0,0}, As[4] = {0,0,0,0};
#pragma unroll
    for (int c = 0; c < NCLS; ++c) {
        float s[4] = {sv[c].x, sv[c].y, sv[c].z, sv[c].w};
        float t[4] = {tv[c].x, tv[c].y, tv[c].z, tv[c].w};
#pragma unroll
        for (int v = 0; v < 4; ++v) {
            float et = __expf(t[v]);
            Zt[v] += et;
            At[v] = fmaf(et, t[v], At[v]);
            As[v] = fmaf(et, s[v], As[v]);
            Zs[v] += __expf(s[v]);
        }
    }

    int cls[4];
    cls[0] = min(max(g.x, 0), NCLS - 1);
    cls[1] = min(max(g.y, 0), NCLS - 1);
    cls[2] = min(max(g.z, 0), NCLS - 1);
    cls[3] = min(max(g.w, 0), NCLS - 1);

    // Sums: per-wave LDS atomics.
#pragma unroll
    for (int v = 0; v < 4; ++v) {
        float kl = (At[v] - As[v]) / Zt[v] - __logf(Zt[v]) + __logf(Zs[v]);
        atomicAdd(&lsum[wave][cls[v]], kl);
    }
    // Counts: ballot + popcount, no atomics.
#pragma unroll
    for (int c = 0; c < NCLS; ++c) {
        int nvc = 0;
#pragma unroll
        for (int v = 0; v < 4; ++v)
            nvc += __popcll(__ballot(cls[v] == c));
        if (lane == 0) lcnt[wave][c] = nvc;
    }

    __syncthreads();
    // Only 14 bins live per block (b uniform): 28 global atomics total.
    if (tid < NCLS) {
        float s = lsum[0][tid] + lsum[1][tid] + lsum[2][tid] + lsum[3][tid];
        int nn = lcnt[0][tid] + lcnt[1][tid] + lcnt[2][tid] + lcnt[3][tid];
        const int slot = blockIdx.x & (KSPREAD - 1);
        const int bin = b * NCLS + tid;
        atomicAdd(&fsum[bin * KSPREAD + slot], s);
        atomicAdd(&fcnt[bin * KSPREAD + slot], nn);
    }
}

__global__ void kd17_final(const float* __restrict__ fsum,
                           const int* __restrict__ fcnt,
                           float* __restrict__ out) {
    __shared__ float terms[64];
    const int t = threadIdx.x;
    float term = 0.0f;
    if (t < NUM_BINS) {
        const float4* fp = reinterpret_cast<const float4*>(fsum + t * KSPREAD);
        const int4* cp = reinterpret_cast<const int4*>(fcnt + t * KSPREAD);
        float s = 0.0f; int n = 0;
#pragma unroll
        for (int i = 0; i < KSPREAD / 4; ++i) {   // fully unrolled: 32 indep loads
            float4 v = fp[i]; s += (v.x + v.y) + (v.z + v.w);
            int4 c = cp[i];   n += (c.x + c.y) + (c.z + c.w);
        }
        const int cls = t % NCLS;   // bin = b*NCLS + cls
        if (cls != 0 && n > 0) term = s / ((float)NCLS * (float)n);
    }
    terms[t] = term;
    __syncthreads();
    if (t == 0) {
        float loss = 0.0f;
#pragma unroll
        for (int i = 0; i < 64; ++i) loss += terms[i];
        out[0] = loss;   // TAU^2 = 1, LOSS_WEIGHT = 1
    }
}

extern "C" void kernel_launch(void* const* d_in, const int* in_sizes, int n_in,
                              void* d_out, int out_size, void* d_ws, size_t ws_size,
                              hipStream_t stream) {
    const float* S = (const float*)d_in[0];
    const float* T = (const float*)d_in[1];
    const int* gt = (const int*)d_in[2];
    float* out = (float*)d_out;

    float* fsum = (float*)d_ws;
    int* fcnt = (int*)((char*)d_ws + NUM_BINS * KSPREAD * sizeof(float));

    const int totalVox = in_sizes[2];       // 1,769,472 = 1728 * 1024
    const int N = totalVox / BATCH;         // 884,736 (divisible by 1024)

    const int block = 256;
    const int grid = totalVox / (block * 4);  // 1728 blocks, 4 voxels/thread

    kd17_zero<<<(NUM_BINS * KSPREAD) / 256, 256, 0, stream>>>(fsum, fcnt);  // 7 blocks
    kd17_kl<<<grid, block, 0, stream>>>(S, T, gt, fsum, fcnt, N);
    kd17_final<<<1, 64, 0, stream>>>(fsum, fcnt, out);
}